// Round 8
// baseline (1676.890 us; speedup 1.0000x reference)
//
#include <hip/hip_runtime.h>

// VQ nearest-codebook: N=262144 rows x D=64, K=1024 codes.
// Numerics contract (bit-exact vs np f32 reference, verified in prior session):
//   dist_k = fl32( fl32(zsq - 2*dot_k) + cbsq_k ), argmin -> lowest index wins.
//   dot_k MUST be one sequential fmaf chain d=0..63 per row. DO NOT re-associate.
//   zsq/cbsq: f64-accumulate then round once.
//
// R11 change: hybrid SMEM-halfA + vector-halfB, ONE lgkm drain per row.
//   Post-mortems: R10 stagger REFUTED convoy theory inverted -- lockstep waves
//   SHARE sK$ line fills (1 miss/8 waves); stagger made 8 distinct streams and
//   throttled the scalar fill path (520->1150us). Lockstep stays.
//   R7's residual 668 cyc/row = TWO lgkmcnt(0) drains/row at ~276 wall-cyc
//   issue->drain distance vs ~500cyc SMEM latency. Full-row SGPR dbuf is
//   impossible (128 SGPR > file), so: P/Q ping-pong now hold halfA (d0..31)
//   of CONSECUTIVE rows -> one drain/row at ~550cyc distance (exposure ~0).
//   halfB (d32..63) comes from vector-global loads double-buffered in named
//   VGPRs (Vc/Vn), issued a full row ahead; vmcnt is INDEPENDENT of lgkmcnt
//   so the two pipes don't interfere. Replication tax halves vs R4/R6.
//   k-loop unrolled x2 so all ping-pong roles are static names.
//   NO per-thread arrays anywhere (scratch hazard) -- all named values.

#define VQ_D 64
#define VQ_MAXK 1024

typedef __attribute__((ext_vector_type(4))) float f4;
typedef const __attribute__((address_space(4))) f4* cb4c_t;
typedef const __attribute__((address_space(4))) float* fc_t;

// Two-row sequential fused-FMA chain step over one float4-worth of c
// (ascending d within each row's chain; chains independent -> ILP without
// reassociation). c may be SGPR-resident (f4) or VGPR (float4).
#define VQ_CH2(qa, qb, c) do { \
    s0 = fmaf((qa).x, (c).x, s0); s1 = fmaf((qb).x, (c).x, s1); \
    s0 = fmaf((qa).y, (c).y, s0); s1 = fmaf((qb).y, (c).y, s1); \
    s0 = fmaf((qa).z, (c).z, s0); s1 = fmaf((qb).z, (c).z, s1); \
    s0 = fmaf((qa).w, (c).w, s0); s1 = fmaf((qb).w, (c).w, s1); } while (0)

// f64 sum-of-squares over one float4 (order-free: tie-invariant).
#define VQ_SQ(acc, q) do { \
    (acc) += (double)(q).x * (double)(q).x; \
    (acc) += (double)(q).y * (double)(q).y; \
    (acc) += (double)(q).z * (double)(q).z; \
    (acc) += (double)(q).w * (double)(q).w; } while (0)

#define SBAR() __builtin_amdgcn_sched_barrier(0)

// kernel1: cbsq[k] = fl32(sum_d f64(cb[k][d]^2)). Same numerics as the old
// in-block prologue (f64 accumulate, round once).
__global__ void vq_cbsq_kernel(const float* __restrict__ cb,
                               float* __restrict__ cbsq, int K)
{
    const int k = blockIdx.x * blockDim.x + threadIdx.x;
    if (k >= K) return;
    const float* c = cb + (size_t)k * VQ_D;
    double s = 0.0;
    #pragma unroll
    for (int d = 0; d < VQ_D; ++d) { double v = (double)c[d]; s += v * v; }
    cbsq[k] = (float)s;
}

template <bool USE_WS>
__global__ __launch_bounds__(256, 2) void vq_argmin_kernel(
    const float* __restrict__ z_e,
    const float* __restrict__ cb,
    const float* __restrict__ cbsq_ws,   // valid iff USE_WS
    float* __restrict__ out,             // [N*D] z_q, then [N] indices (as float)
    int N, int K)
{
    __shared__ float s_cbsq[VQ_MAXK];    // used only if !USE_WS

    if (!USE_WS) {
        for (int k = threadIdx.x; k < K; k += blockDim.x) {
            const float* c = cb + (size_t)k * VQ_D;
            double s = 0.0;
            #pragma unroll
            for (int d = 0; d < VQ_D; ++d) { double v = (double)c[d]; s += v * v; }
            s_cbsq[k] = (float)s;
        }
        __syncthreads();
    }

    // Two rows per thread: n0 = b*512 + t, n1 = n0 + 256.
    int n0 = blockIdx.x * (2 * (int)blockDim.x) + threadIdx.x;
    if (n0 >= N) return;                 // after the (optional) barrier: legal
    int n1 = n0 + (int)blockDim.x;
    if (n1 >= N) n1 = n0;                // harmless duplicate; never hit here

    // Both z rows in 32 NAMED float4 registers (NOT arrays — scratch hazard).
    const float4* zp0 = (const float4*)(z_e + (size_t)n0 * VQ_D);
    const float4* zp1 = (const float4*)(z_e + (size_t)n1 * VQ_D);
    float4 a0  = zp0[0],  a1  = zp0[1],  a2  = zp0[2],  a3  = zp0[3];
    float4 a4  = zp0[4],  a5  = zp0[5],  a6  = zp0[6],  a7  = zp0[7];
    float4 a8  = zp0[8],  a9  = zp0[9],  a10 = zp0[10], a11 = zp0[11];
    float4 a12 = zp0[12], a13 = zp0[13], a14 = zp0[14], a15 = zp0[15];
    float4 b0  = zp1[0],  b1  = zp1[1],  b2  = zp1[2],  b3  = zp1[3];
    float4 b4  = zp1[4],  b5  = zp1[5],  b6  = zp1[6],  b7  = zp1[7];
    float4 b8  = zp1[8],  b9  = zp1[9],  b10 = zp1[10], b11 = zp1[11];
    float4 b12 = zp1[12], b13 = zp1[13], b14 = zp1[14], b15 = zp1[15];

    // ||z||^2 in f64, rounded once (per row). Done BEFORE issuing the V
    // prefetches to keep the f64-temp pressure off the loop's peak.
    double zs0 = 0.0, zs1 = 0.0;
    VQ_SQ(zs0, a0);  VQ_SQ(zs0, a1);  VQ_SQ(zs0, a2);  VQ_SQ(zs0, a3);
    VQ_SQ(zs0, a4);  VQ_SQ(zs0, a5);  VQ_SQ(zs0, a6);  VQ_SQ(zs0, a7);
    VQ_SQ(zs0, a8);  VQ_SQ(zs0, a9);  VQ_SQ(zs0, a10); VQ_SQ(zs0, a11);
    VQ_SQ(zs0, a12); VQ_SQ(zs0, a13); VQ_SQ(zs0, a14); VQ_SQ(zs0, a15);
    VQ_SQ(zs1, b0);  VQ_SQ(zs1, b1);  VQ_SQ(zs1, b2);  VQ_SQ(zs1, b3);
    VQ_SQ(zs1, b4);  VQ_SQ(zs1, b5);  VQ_SQ(zs1, b6);  VQ_SQ(zs1, b7);
    VQ_SQ(zs1, b8);  VQ_SQ(zs1, b9);  VQ_SQ(zs1, b10); VQ_SQ(zs1, b11);
    VQ_SQ(zs1, b12); VQ_SQ(zs1, b13); VQ_SQ(zs1, b14); VQ_SQ(zs1, b15);
    const float zsq0 = (float)zs0;
    const float zsq1 = (float)zs1;

    // Constant-AS views -> uniform loads become s_load (SGPR-resident halfA).
    cb4c_t cbc = (cb4c_t)(unsigned long long)cb;      // 16 f4 per row
    fc_t   sqc = (fc_t)(unsigned long long)cbsq_ws;
    const float4* cbv = (const float4*)cb;            // vector view for halfB

    float best0 = 3.4e38f, best1 = 3.4e38f;
    int bk0 = 0, bk1 = 0;

    // SMEM halfA ping-pong: P = even rows, Q = odd rows (32 SGPR each).
    f4 P0, P1, P2, P3, P4, P5, P6, P7;
    f4 Q0, Q1, Q2, Q3, Q4, Q5, Q6, Q7;
    float cqP, cqQ;
    // Vector halfB double-buffer: Vc = even rows, Vn = odd rows (named VGPRs).
    float4 Vc0, Vc1, Vc2, Vc3, Vc4, Vc5, Vc6, Vc7;
    float4 Vn0, Vn1, Vn2, Vn3, Vn4, Vn5, Vn6, Vn7;

    // Prologue: P := halfA(0)+cbsq(0) [SMEM, drained at row 0's first FMA];
    // Vc := halfB(0), Vn := halfB(1) [VMEM, vmcnt-tracked by compiler].
    P0 = cbc[0]; P1 = cbc[1]; P2 = cbc[2]; P3 = cbc[3];
    P4 = cbc[4]; P5 = cbc[5]; P6 = cbc[6]; P7 = cbc[7];
    cqP = USE_WS ? sqc[0] : s_cbsq[0];
    {
        const float4* g0 = cbv + 8;        // row 0, d32..63
        Vc0 = g0[0]; Vc1 = g0[1]; Vc2 = g0[2]; Vc3 = g0[3];
        Vc4 = g0[4]; Vc5 = g0[5]; Vc6 = g0[6]; Vc7 = g0[7];
        const float4* g1 = cbv + 16 + 8;   // row 1, d32..63
        Vn0 = g1[0]; Vn1 = g1[1]; Vn2 = g1[2]; Vn3 = g1[3];
        Vn4 = g1[4]; Vn5 = g1[5]; Vn6 = g1[6]; Vn7 = g1[7];
    }

    #pragma unroll 1
    for (int k = 0; k < K; k += 2) {
        // ================= row k (even): halfA in P, halfB in Vc ============
        {
            float s0 = 0.f, s1 = 0.f;
            // First P use: lgkmcnt(0) lands here. Only P(+cqP) is outstanding
            // (issued ~1 row ago in the odd body) -> exposure ~0.
            VQ_CH2(a0, b0, P0);
            SBAR();
            // Issue box: Q := halfA(k+1) + cbsq(k+1). Sole outstanding SMEM
            // until the odd body's first Q use (~1 row away).
            {
                const int nb = (k + 1) << 4;
                Q0 = cbc[nb + 0]; Q1 = cbc[nb + 1]; Q2 = cbc[nb + 2]; Q3 = cbc[nb + 3];
                Q4 = cbc[nb + 4]; Q5 = cbc[nb + 5]; Q6 = cbc[nb + 6]; Q7 = cbc[nb + 7];
                cqQ = USE_WS ? sqc[k + 1] : s_cbsq[k + 1];
            }
            SBAR();
            // Rest of halfA (d4..31), sequential ascending d.
            VQ_CH2(a1, b1, P1); VQ_CH2(a2, b2, P2); VQ_CH2(a3, b3, P3);
            VQ_CH2(a4, b4, P4); VQ_CH2(a5, b5, P5); VQ_CH2(a6, b6, P6);
            VQ_CH2(a7, b7, P7);
            // halfB (d32..63) from VGPRs; compiler places counted vmcnt wait
            // (Vc issued ~2 rows ago; Vn still allowed outstanding).
            VQ_CH2(a8,  b8,  Vc0); VQ_CH2(a9,  b9,  Vc1);
            VQ_CH2(a10, b10, Vc2); VQ_CH2(a11, b11, Vc3);
            VQ_CH2(a12, b12, Vc4); VQ_CH2(a13, b13, Vc5);
            VQ_CH2(a14, b14, Vc6); VQ_CH2(a15, b15, Vc7);
            // Reissue Vc := halfB(k+2) (clamped; refetch unused, never OOB).
            {
                int nk = k + 2; if (nk >= K) nk = K - 2;
                const float4* gp = cbv + ((size_t)nk << 4) + 8;
                Vc0 = gp[0]; Vc1 = gp[1]; Vc2 = gp[2]; Vc3 = gp[3];
                Vc4 = gp[4]; Vc5 = gp[5]; Vc6 = gp[6]; Vc7 = gp[7];
            }
            const float u0    = zsq0 - 2.0f * s0;   // 2*s exact; fp32 round
            const float dist0 = u0 + cqP;           // fp32 round, as reference
            const float u1    = zsq1 - 2.0f * s1;
            const float dist1 = u1 + cqP;
            if (dist0 < best0) { best0 = dist0; bk0 = k; }  // strict <
            if (dist1 < best1) { best1 = dist1; bk1 = k; }
        }
        // ================= row k+1 (odd): halfA in Q, halfB in Vn ===========
        {
            float s0 = 0.f, s1 = 0.f;
            // First Q use: lgkmcnt(0) drains Q(+cqQ), issued ~1 row ago.
            VQ_CH2(a0, b0, Q0);
            SBAR();
            // Issue box: P := halfA(k+2) + cbsq(k+2) (clamped last iter).
            {
                int nk = k + 2; if (nk >= K) nk = K - 2;
                const int nb = nk << 4;
                P0 = cbc[nb + 0]; P1 = cbc[nb + 1]; P2 = cbc[nb + 2]; P3 = cbc[nb + 3];
                P4 = cbc[nb + 4]; P5 = cbc[nb + 5]; P6 = cbc[nb + 6]; P7 = cbc[nb + 7];
                cqP = USE_WS ? sqc[nk] : s_cbsq[nk];
            }
            SBAR();
            VQ_CH2(a1, b1, Q1); VQ_CH2(a2, b2, Q2); VQ_CH2(a3, b3, Q3);
            VQ_CH2(a4, b4, Q4); VQ_CH2(a5, b5, Q5); VQ_CH2(a6, b6, Q6);
            VQ_CH2(a7, b7, Q7);
            VQ_CH2(a8,  b8,  Vn0); VQ_CH2(a9,  b9,  Vn1);
            VQ_CH2(a10, b10, Vn2); VQ_CH2(a11, b11, Vn3);
            VQ_CH2(a12, b12, Vn4); VQ_CH2(a13, b13, Vn5);
            VQ_CH2(a14, b14, Vn6); VQ_CH2(a15, b15, Vn7);
            // Reissue Vn := halfB(k+3) (clamped; refetch unused, never OOB).
            {
                int nk = k + 3; if (nk >= K) nk = K - 1;
                const float4* gp = cbv + ((size_t)nk << 4) + 8;
                Vn0 = gp[0]; Vn1 = gp[1]; Vn2 = gp[2]; Vn3 = gp[3];
                Vn4 = gp[4]; Vn5 = gp[5]; Vn6 = gp[6]; Vn7 = gp[7];
            }
            const float u0    = zsq0 - 2.0f * s0;
            const float dist0 = u0 + cqQ;
            const float u1    = zsq1 - 2.0f * s1;
            const float dist1 = u1 + cqQ;
            if (dist0 < best0) { best0 = dist0; bk0 = k + 1; }
            if (dist1 < best1) { best1 = dist1; bk1 = k + 1; }
        }
    }

    // z_q gathers (divergent index -> per-lane VMEM; codebook L2-resident).
    {
        const float4* cq0 = (const float4*)(cb + (size_t)bk0 * VQ_D);
        float4* oq0 = (float4*)(out + (size_t)n0 * VQ_D);
        #pragma unroll
        for (int i = 0; i < VQ_D / 4; ++i) oq0[i] = cq0[i];
        const float4* cq1 = (const float4*)(cb + (size_t)bk1 * VQ_D);
        float4* oq1 = (float4*)(out + (size_t)n1 * VQ_D);
        #pragma unroll
        for (int i = 0; i < VQ_D / 4; ++i) oq1[i] = cq1[i];
    }

    // Indices as float (exact for k < 2^24).
    out[(size_t)N * VQ_D + n0] = (float)bk0;
    out[(size_t)N * VQ_D + n1] = (float)bk1;
}

extern "C" void kernel_launch(void* const* d_in, const int* in_sizes, int n_in,
                              void* d_out, int out_size, void* d_ws, size_t ws_size,
                              hipStream_t stream) {
    const float* z_e = (const float*)d_in[0];
    const float* cb  = (const float*)d_in[1];
    float* out = (float*)d_out;

    const int N = in_sizes[0] / VQ_D;
    const int K = in_sizes[1] / VQ_D;

    const int block = 256;
    const int rows_per_block = 2 * block;
    const int grid = (N + rows_per_block - 1) / rows_per_block;

    const bool use_ws = (d_ws != nullptr) && (ws_size >= (size_t)K * sizeof(float));
    if (use_ws) {
        float* cbsq = (float*)d_ws;
        vq_cbsq_kernel<<<(K + 255) / 256, 256, 0, stream>>>(cb, cbsq, K);
        vq_argmin_kernel<true><<<grid, block, 0, stream>>>(z_e, cb, cbsq, out, N, K);
    } else {
        vq_argmin_kernel<false><<<grid, block, 0, stream>>>(z_e, cb, nullptr, out, N, K);
    }
}

// Round 9
// 584.972 us; speedup vs baseline: 2.8666x; 2.8666x over previous
//
#include <hip/hip_runtime.h>

// VQ nearest-codebook: N=262144 rows x D=64, K=1024 codes.
// Numerics contract (bit-exact vs np f32 reference, verified in prior session):
//   dist_k = fl32( fl32(zsq - 2*dot_k) + cbsq_k ), argmin -> lowest index wins.
//   dot_k MUST be one sequential fmaf chain d=0..63 per row. DO NOT re-associate.
//   zsq/cbsq: f64-accumulate then round once.
//
// R12 change: R7 kernel (best, 520us) + amdgpu_waves_per_eu(2,2).
//   Diagnosis (R4-R11 cross-exam): reported VGPR_Count (88 raw for R7) is far
//   below the 128 VGPRs the two z-rows need -> the allocator was REMATERIALIZING
//   ~15 z float4 loads per K-iteration (L1/L2-hit, so invisible in FETCH/WRITE).
//   That remat stream is the common ~1200cyc/row term across R4/R6/R7 and why
//   VALUBusy pinned ~50%. The occupancy heuristic that drives remat is moot
//   here: the grid supplies only 2 blocks/CU = 2 waves/SIMD. waves_per_eu(2,2)
//   clamps the allocator target to exactly that -> VGPR budget 256, q stays
//   resident, inner loop = 16 s_loads + 128 FMAs + ~0 VMEM.
//   Gate in counters: VGPR_Count >= ~150. Tripwire: WRITE >> 70MB = true spill.
//   R11 (hybrid halfB-VMEM) made remat worse (1650us) -> reverted entirely.
//   NO per-thread arrays anywhere (scratch hazard) -- all named values.

#define VQ_D 64
#define VQ_MAXK 1024

typedef __attribute__((ext_vector_type(4))) float f4;
typedef const __attribute__((address_space(4))) f4* cb4c_t;
typedef const __attribute__((address_space(4))) float* fc_t;

// Two-row sequential fused-FMA chain step over one float4-worth of c
// (ascending d within each row's chain; chains independent -> ILP without
// reassociation). c is an SGPR-resident f4.
#define VQ_CH2(qa, qb, c) do { \
    s0 = fmaf((qa).x, (c).x, s0); s1 = fmaf((qb).x, (c).x, s1); \
    s0 = fmaf((qa).y, (c).y, s0); s1 = fmaf((qb).y, (c).y, s1); \
    s0 = fmaf((qa).z, (c).z, s0); s1 = fmaf((qb).z, (c).z, s1); \
    s0 = fmaf((qa).w, (c).w, s0); s1 = fmaf((qb).w, (c).w, s1); } while (0)

// f64 sum-of-squares over one float4 (order-free: tie-invariant).
#define VQ_SQ(acc, q) do { \
    (acc) += (double)(q).x * (double)(q).x; \
    (acc) += (double)(q).y * (double)(q).y; \
    (acc) += (double)(q).z * (double)(q).z; \
    (acc) += (double)(q).w * (double)(q).w; } while (0)

#define SBAR() __builtin_amdgcn_sched_barrier(0)

// kernel1: cbsq[k] = fl32(sum_d f64(cb[k][d]^2)). Same numerics as the old
// in-block prologue (f64 accumulate, round once).
__global__ void vq_cbsq_kernel(const float* __restrict__ cb,
                               float* __restrict__ cbsq, int K)
{
    const int k = blockIdx.x * blockDim.x + threadIdx.x;
    if (k >= K) return;
    const float* c = cb + (size_t)k * VQ_D;
    double s = 0.0;
    #pragma unroll
    for (int d = 0; d < VQ_D; ++d) { double v = (double)c[d]; s += v * v; }
    cbsq[k] = (float)s;
}

template <bool USE_WS>
__global__ __launch_bounds__(256)
__attribute__((amdgpu_waves_per_eu(2, 2)))
void vq_argmin_kernel(
    const float* __restrict__ z_e,
    const float* __restrict__ cb,
    const float* __restrict__ cbsq_ws,   // valid iff USE_WS
    float* __restrict__ out,             // [N*D] z_q, then [N] indices (as float)
    int N, int K)
{
    __shared__ float s_cbsq[VQ_MAXK];    // used only if !USE_WS

    if (!USE_WS) {
        for (int k = threadIdx.x; k < K; k += blockDim.x) {
            const float* c = cb + (size_t)k * VQ_D;
            double s = 0.0;
            #pragma unroll
            for (int d = 0; d < VQ_D; ++d) { double v = (double)c[d]; s += v * v; }
            s_cbsq[k] = (float)s;
        }
        __syncthreads();
    }

    // Two rows per thread: n0 = b*512 + t, n1 = n0 + 256.
    int n0 = blockIdx.x * (2 * (int)blockDim.x) + threadIdx.x;
    if (n0 >= N) return;                 // after the (optional) barrier: legal
    int n1 = n0 + (int)blockDim.x;
    if (n1 >= N) n1 = n0;                // harmless duplicate; never hit here

    // Both z rows in 32 NAMED float4 registers (NOT arrays — scratch hazard).
    const float4* zp0 = (const float4*)(z_e + (size_t)n0 * VQ_D);
    const float4* zp1 = (const float4*)(z_e + (size_t)n1 * VQ_D);
    float4 a0  = zp0[0],  a1  = zp0[1],  a2  = zp0[2],  a3  = zp0[3];
    float4 a4  = zp0[4],  a5  = zp0[5],  a6  = zp0[6],  a7  = zp0[7];
    float4 a8  = zp0[8],  a9  = zp0[9],  a10 = zp0[10], a11 = zp0[11];
    float4 a12 = zp0[12], a13 = zp0[13], a14 = zp0[14], a15 = zp0[15];
    float4 b0  = zp1[0],  b1  = zp1[1],  b2  = zp1[2],  b3  = zp1[3];
    float4 b4  = zp1[4],  b5  = zp1[5],  b6  = zp1[6],  b7  = zp1[7];
    float4 b8  = zp1[8],  b9  = zp1[9],  b10 = zp1[10], b11 = zp1[11];
    float4 b12 = zp1[12], b13 = zp1[13], b14 = zp1[14], b15 = zp1[15];

    // ||z||^2 in f64, rounded once (per row).
    double zs0 = 0.0, zs1 = 0.0;
    VQ_SQ(zs0, a0);  VQ_SQ(zs0, a1);  VQ_SQ(zs0, a2);  VQ_SQ(zs0, a3);
    VQ_SQ(zs0, a4);  VQ_SQ(zs0, a5);  VQ_SQ(zs0, a6);  VQ_SQ(zs0, a7);
    VQ_SQ(zs0, a8);  VQ_SQ(zs0, a9);  VQ_SQ(zs0, a10); VQ_SQ(zs0, a11);
    VQ_SQ(zs0, a12); VQ_SQ(zs0, a13); VQ_SQ(zs0, a14); VQ_SQ(zs0, a15);
    VQ_SQ(zs1, b0);  VQ_SQ(zs1, b1);  VQ_SQ(zs1, b2);  VQ_SQ(zs1, b3);
    VQ_SQ(zs1, b4);  VQ_SQ(zs1, b5);  VQ_SQ(zs1, b6);  VQ_SQ(zs1, b7);
    VQ_SQ(zs1, b8);  VQ_SQ(zs1, b9);  VQ_SQ(zs1, b10); VQ_SQ(zs1, b11);
    VQ_SQ(zs1, b12); VQ_SQ(zs1, b13); VQ_SQ(zs1, b14); VQ_SQ(zs1, b15);
    const float zsq0 = (float)zs0;
    const float zsq1 = (float)zs1;

    // Constant-AS views -> uniform loads become s_load (SGPR-resident rows).
    cb4c_t cbc = (cb4c_t)(unsigned long long)cb;      // 16 f4 per row
    fc_t   sqc = (fc_t)(unsigned long long)cbsq_ws;

    float best0 = 3.4e38f, best1 = 3.4e38f;
    int bk0 = 0, bk1 = 0;

    // Half-row ping-pong buffers (SGPR f4s). X = d0..31, Y = d32..63.
    f4 X0, X1, X2, X3, X4, X5, X6, X7;
    f4 Y0, Y1, Y2, Y3, Y4, Y5, Y6, Y7;
    float cq;

    // Prologue: issue A(0) into X. (One-time short-distance wait at k=0.)
    X0 = cbc[0]; X1 = cbc[1]; X2 = cbc[2]; X3 = cbc[3];
    X4 = cbc[4]; X5 = cbc[5]; X6 = cbc[6]; X7 = cbc[7];

    #pragma unroll 1
    for (int k = 0; k < K; ++k) {
        const int kb = k << 4;
        float s0 = 0.f, s1 = 0.f;

        // First X use: lgkmcnt(0) lands HERE, draining X issued mid-B-block of
        // the previous iteration.
        VQ_CH2(a0, b0, X0);
        SBAR();
        // Issue box: B(k) -> Y, plus cbsq(k). Boxed so the scheduler can
        // neither hoist these above the X-wait nor sink them toward their use.
        Y0 = cbc[kb + 8];  Y1 = cbc[kb + 9];  Y2 = cbc[kb + 10]; Y3 = cbc[kb + 11];
        Y4 = cbc[kb + 12]; Y5 = cbc[kb + 13]; Y6 = cbc[kb + 14]; Y7 = cbc[kb + 15];
        cq = USE_WS ? sqc[k] : s_cbsq[k];
        SBAR();
        // Rest of A-half (d4..31), sequential ascending d.
        VQ_CH2(a1, b1, X1); VQ_CH2(a2, b2, X2); VQ_CH2(a3, b3, X3);
        VQ_CH2(a4, b4, X4); VQ_CH2(a5, b5, X5); VQ_CH2(a6, b6, X6);
        VQ_CH2(a7, b7, X7);

        // First Y use: lgkmcnt(0) lands HERE, draining Y+cq.
        VQ_CH2(a8, b8, Y0);
        SBAR();
        // Issue box: A(k+1) -> X (clamped last iter; 64B reload, harmless).
        {
            int nk = k + 1; if (nk >= K) nk = K - 1;
            const int nb = nk << 4;
            X0 = cbc[nb + 0]; X1 = cbc[nb + 1]; X2 = cbc[nb + 2]; X3 = cbc[nb + 3];
            X4 = cbc[nb + 4]; X5 = cbc[nb + 5]; X6 = cbc[nb + 6]; X7 = cbc[nb + 7];
        }
        SBAR();
        // Rest of B-half (d36..63), sequential ascending d.
        VQ_CH2(a9,  b9,  Y1); VQ_CH2(a10, b10, Y2); VQ_CH2(a11, b11, Y3);
        VQ_CH2(a12, b12, Y4); VQ_CH2(a13, b13, Y5); VQ_CH2(a14, b14, Y6);
        VQ_CH2(a15, b15, Y7);

        // cq completed at the Y-wait; no further lgkm wait needed here.
        const float u0    = zsq0 - 2.0f * s0;   // 2*s exact; one fp32 round
        const float dist0 = u0 + cq;            // fp32 round, as reference
        const float u1    = zsq1 - 2.0f * s1;
        const float dist1 = u1 + cq;
        if (dist0 < best0) { best0 = dist0; bk0 = k; }  // strict <: lowest k
        if (dist1 < best1) { best1 = dist1; bk1 = k; }
    }

    // z_q gathers (divergent index -> per-lane VMEM; codebook L2-resident).
    {
        const float4* cq0 = (const float4*)(cb + (size_t)bk0 * VQ_D);
        float4* oq0 = (float4*)(out + (size_t)n0 * VQ_D);
        #pragma unroll
        for (int i = 0; i < VQ_D / 4; ++i) oq0[i] = cq0[i];
        const float4* cq1 = (const float4*)(cb + (size_t)bk1 * VQ_D);
        float4* oq1 = (float4*)(out + (size_t)n1 * VQ_D);
        #pragma unroll
        for (int i = 0; i < VQ_D / 4; ++i) oq1[i] = cq1[i];
    }

    // Indices as float (exact for k < 2^24).
    out[(size_t)N * VQ_D + n0] = (float)bk0;
    out[(size_t)N * VQ_D + n1] = (float)bk1;
}

extern "C" void kernel_launch(void* const* d_in, const int* in_sizes, int n_in,
                              void* d_out, int out_size, void* d_ws, size_t ws_size,
                              hipStream_t stream) {
    const float* z_e = (const float*)d_in[0];
    const float* cb  = (const float*)d_in[1];
    float* out = (float*)d_out;

    const int N = in_sizes[0] / VQ_D;
    const int K = in_sizes[1] / VQ_D;

    const int block = 256;
    const int rows_per_block = 2 * block;
    const int grid = (N + rows_per_block - 1) / rows_per_block;

    const bool use_ws = (d_ws != nullptr) && (ws_size >= (size_t)K * sizeof(float));
    if (use_ws) {
        float* cbsq = (float*)d_ws;
        vq_cbsq_kernel<<<(K + 255) / 256, 256, 0, stream>>>(cb, cbsq, K);
        vq_argmin_kernel<true><<<grid, block, 0, stream>>>(z_e, cb, cbsq, out, N, K);
    } else {
        vq_argmin_kernel<false><<<grid, block, 0, stream>>>(z_e, cb, nullptr, out, N, K);
    }
}